// Round 3
// baseline (382.453 us; speedup 1.0000x reference)
//
#include <hip/hip_runtime.h>
#include <hip/hip_bf16.h>
#include <math.h>

#define N_CELL 76
#define N_DRUG 764
#define N_ITEM 840
#define BATCH  4096

// ws layout (byte offsets)
// pool1  f32 [840][64][64][4ch] interleaved : 0          .. 55,050,240
// pool2  bf16 [848][8192] (8 rows pad)      : 55,050,240 .. 68,943,872
// wbf    bf16 [64][8192]                    : 68,943,872 .. 69,992,448
// xfc    f32 [840][64]                      : 69,992,448 .. 70,207,488
// item   f32 [840][64]                      : 70,207,488 .. 70,422,528
// emb    f32 [840][64]                      : 70,422,528 .. 70,637,568
// loss   f32 scalar                         : 70,637,568
#define POOL2_B 55050240u
#define WBF_B   68943872u
#define XFC_B   69992448u
#define ITEM_B  70207488u
#define EMB_B   70422528u
#define LOSS_B  70637568u

typedef short bh8 __attribute__((ext_vector_type(8)));
typedef float f32x4 __attribute__((ext_vector_type(4)));

static __device__ inline unsigned short f2bf(float f) {
  union { float f; unsigned u; } v; v.f = f;
  unsigned r = v.u + 0x7FFFu + ((v.u >> 16) & 1u);  // RNE (no NaN inputs here)
  return (unsigned short)(r >> 16);
}

// ---------------- cast out_w -> bf16, zero xfc ----------------
__global__ __launch_bounds__(256) void k_cast(
    const float* __restrict__ out_w, unsigned short* __restrict__ wbf,
    float* __restrict__ xfc) {
  int gid = blockIdx.x * 256 + threadIdx.x;  // 0..131071 (exact: 524288/4)
  float4 v = ((const float4*)out_w)[gid];
  ushort4 o;
  o.x = f2bf(v.x); o.y = f2bf(v.y); o.z = f2bf(v.z); o.w = f2bf(v.w);
  ((ushort4*)wbf)[gid] = o;
  if (gid < N_ITEM * 64) xfc[gid] = 0.f;
}

// ---------------- conv1 (1->4ch, 3x3 SAME) + relu + maxpool2 ----------------
// grid (2, 840). Thread: 4 conv cols (aligned b128 LDS read, halo via shfl),
// 2 conv rows -> 2 pool px intra-thread. Writes pool1 interleaved [py][px][4c].
__global__ __launch_bounds__(256, 4) void k_conv1(
    const float* __restrict__ cell_pre, const float* __restrict__ drug_pre,
    const float* __restrict__ w1, const float* __restrict__ b1,
    float* __restrict__ pool1, float* __restrict__ loss) {
  __shared__ float img[66 * 128];  // row r = image row (cy0-1+r), zero-filled OOB
  int half = blockIdx.x, n = blockIdx.y;
  int tid = threadIdx.x;
  if (half == 0 && n == 0 && tid == 0) *loss = 0.f;  // stream-ordered zero init
  int cy0 = half * 64;
  const float* src = (n < N_CELL) ? (cell_pre + (size_t)n * 16384)
                                  : (drug_pre + (size_t)(n - N_CELL) * 16384);
  for (int i = tid; i < 66 * 32; i += 256) {
    int r = i >> 5, c = i & 31;
    int iy = cy0 - 1 + r;
    float4 v = make_float4(0.f, 0.f, 0.f, 0.f);
    if (iy >= 0 && iy < 128) v = ((const float4*)src)[iy * 32 + c];
    ((float4*)img)[i] = v;
  }
  float wv[4][9], bb[4];
#pragma unroll
  for (int c = 0; c < 4; ++c) {
    bb[c] = b1[c];
#pragma unroll
    for (int j = 0; j < 9; ++j) wv[c][j] = w1[c * 9 + j];
  }
  __syncthreads();
  int t = tid & 31;   // col group: conv cols 4t..4t+3
  int g = tid >> 5;   // 0..7 row groups
  const float4* img4 = (const float4*)img;
  for (int rpi = 0; rpi < 4; ++rpi) {
    int rp = g + 8 * rpi;  // local pool row 0..31
    int ly = 2 * rp;       // conv rows ly, ly+1 -> LDS rows ly..ly+3
    float4 rowv[4]; float lo[4], hi[4];
#pragma unroll
    for (int rr = 0; rr < 4; ++rr) {
      rowv[rr] = img4[(ly + rr) * 32 + t];
      float l = __shfl_up(rowv[rr].w, 1);
      float h = __shfl_down(rowv[rr].x, 1);
      lo[rr] = (t == 0) ? 0.f : l;   // col -1 SAME-pad
      hi[rr] = (t == 31) ? 0.f : h;  // col 128 SAME-pad
    }
    float a[2][4][4];
#pragma unroll
    for (int orow = 0; orow < 2; ++orow)
#pragma unroll
      for (int oc = 0; oc < 4; ++oc)
#pragma unroll
        for (int c = 0; c < 4; ++c) a[orow][oc][c] = bb[oc];
#pragma unroll
    for (int orow = 0; orow < 2; ++orow) {
#pragma unroll
      for (int kr = 0; kr < 3; ++kr) {
        int rr = orow + kr;
        float in[6] = {lo[rr], rowv[rr].x, rowv[rr].y, rowv[rr].z, rowv[rr].w, hi[rr]};
#pragma unroll
        for (int ks = 0; ks < 3; ++ks)
#pragma unroll
          for (int oc = 0; oc < 4; ++oc) {
            float w = wv[oc][kr * 3 + ks];
#pragma unroll
            for (int c = 0; c < 4; ++c) a[orow][oc][c] += in[c + ks] * w;
          }
      }
    }
#pragma unroll
    for (int pc = 0; pc < 2; ++pc) {
      float4 res;
      float* resf = (float*)&res;
#pragma unroll
      for (int oc = 0; oc < 4; ++oc) {
        float m = fmaxf(fmaxf(a[0][oc][2 * pc], a[0][oc][2 * pc + 1]),
                        fmaxf(a[1][oc][2 * pc], a[1][oc][2 * pc + 1]));
        resf[oc] = fmaxf(m, 0.f);
      }
      int py = half * 32 + rp, px = 2 * t + pc;
      ((float4*)pool1)[((size_t)n * 64 + py) * 64 + px] = res;
    }
  }
}

// ---------------- conv2 (4->8ch, 3x3 SAME) + relu + maxpool2 -> bf16 ----------------
// grid (2, 840). (kr,ks)-major: 64 live accumulators, weights chunked 32/step
// into SGPRs, zero-padded LDS borders (no bounds cndmask), b128 reads only.
__global__ __launch_bounds__(256, 4) void k_conv2(
    const float* __restrict__ pool1, const float* __restrict__ w2,
    const float* __restrict__ b2, unsigned short* __restrict__ pool2) {
  __shared__ float p1[34 * 66 * 4];  // [row][col 0..65][4ch]; col0/col65 = zero
  int half = blockIdx.x, n = blockIdx.y;
  int tid = threadIdx.x;
  int cy0 = half * 32;
  const float4* src = (const float4*)(pool1 + (size_t)n * 16384);
  for (int i = tid; i < 34 * 64; i += 256) {
    int r = i >> 6, c = i & 63;
    int iy = cy0 - 1 + r;
    float4 v = make_float4(0.f, 0.f, 0.f, 0.f);
    if (iy >= 0 && iy < 64) v = src[iy * 64 + c];
    ((float4*)p1)[r * 66 + c + 1] = v;
  }
  if (tid < 68) {
    int r = tid >> 1, c = (tid & 1) ? 65 : 0;
    ((float4*)p1)[r * 66 + c] = make_float4(0.f, 0.f, 0.f, 0.f);
  }
  float bb[8];
#pragma unroll
  for (int o = 0; o < 8; ++o) bb[o] = b2[o];
  __syncthreads();
  int x = tid & 63;  // conv column
  int w = tid >> 6;  // wave -> pool rows w, w+4, w+8, w+12
  const float4* p14 = (const float4*)p1;
  float acc[4][2][8];
#pragma unroll
  for (int rpi = 0; rpi < 4; ++rpi)
#pragma unroll
    for (int rr = 0; rr < 2; ++rr)
#pragma unroll
      for (int oc = 0; oc < 8; ++oc) acc[rpi][rr][oc] = bb[oc];
#pragma unroll
  for (int kr = 0; kr < 3; ++kr) {
#pragma unroll
    for (int ks = 0; ks < 3; ++ks) {
      float wv[8][4];  // uniform loads -> scalar regs
#pragma unroll
      for (int oc = 0; oc < 8; ++oc)
#pragma unroll
        for (int ic = 0; ic < 4; ++ic)
          wv[oc][ic] = w2[((oc * 4 + ic) * 3 + kr) * 3 + ks];
#pragma unroll
      for (int rpi = 0; rpi < 4; ++rpi) {
        int rp = w + 4 * rpi;
        float4 v0 = p14[(2 * rp + kr) * 66 + x + ks];
        float4 v1 = p14[(2 * rp + 1 + kr) * 66 + x + ks];
#pragma unroll
        for (int oc = 0; oc < 8; ++oc) {
          acc[rpi][0][oc] += v0.x * wv[oc][0] + v0.y * wv[oc][1] +
                             v0.z * wv[oc][2] + v0.w * wv[oc][3];
          acc[rpi][1][oc] += v1.x * wv[oc][0] + v1.y * wv[oc][1] +
                             v1.z * wv[oc][2] + v1.w * wv[oc][3];
        }
      }
    }
  }
#pragma unroll
  for (int rpi = 0; rpi < 4; ++rpi) {
    int rp = w + 4 * rpi;
    int py = half * 16 + rp, px = x >> 1;
#pragma unroll
    for (int oc = 0; oc < 8; ++oc) {
      float m = fmaxf(fmaxf(acc[rpi][0][oc], acc[rpi][1][oc]), 0.f);
      m = fmaxf(m, __shfl_xor(m, 1));
      if ((x & 1) == 0)
        pool2[(size_t)n * 8192 + oc * 1024 + py * 32 + px] = f2bf(m);
    }
  }
}

// ---------------- FC: bf16 MFMA GEMM, M=840 N=64, K chunks of 256 ----------------
// grid (53 M-tiles, 32 K-chunks), 64 threads (1 wave). atomicAdd into xfc.
// out_b omitted: it cancels exactly in the per-column batch norm.
__global__ __launch_bounds__(64) void k_fc(
    const unsigned short* __restrict__ pool2, const unsigned short* __restrict__ wbf,
    float* __restrict__ xfc) {
  int mt = blockIdx.x, kc = blockIdx.y;
  int lane = threadIdx.x;
  int ml = lane & 15, q = lane >> 4;
  size_t k0 = (size_t)kc * 256 + q * 8;
  const bh8* A  = (const bh8*)(pool2 + (size_t)(mt * 16 + ml) * 8192 + k0);  // rows<848 alloc'd
  const bh8* B0 = (const bh8*)(wbf + (size_t)(ml) * 8192 + k0);
  const bh8* B1 = (const bh8*)(wbf + (size_t)(16 + ml) * 8192 + k0);
  const bh8* B2 = (const bh8*)(wbf + (size_t)(32 + ml) * 8192 + k0);
  const bh8* B3 = (const bh8*)(wbf + (size_t)(48 + ml) * 8192 + k0);
  f32x4 acc0 = {0.f, 0.f, 0.f, 0.f}, acc1 = acc0, acc2 = acc0, acc3 = acc0;
#pragma unroll
  for (int st = 0; st < 8; ++st) {
    bh8 a = A[st * 4];  // 32 bf16 step = 4 x 16B
    bh8 b0 = B0[st * 4], b1 = B1[st * 4], b2v = B2[st * 4], b3 = B3[st * 4];
    acc0 = __builtin_amdgcn_mfma_f32_16x16x32_bf16(a, b0, acc0, 0, 0, 0);
    acc1 = __builtin_amdgcn_mfma_f32_16x16x32_bf16(a, b1, acc1, 0, 0, 0);
    acc2 = __builtin_amdgcn_mfma_f32_16x16x32_bf16(a, b2v, acc2, 0, 0, 0);
    acc3 = __builtin_amdgcn_mfma_f32_16x16x32_bf16(a, b3, acc3, 0, 0, 0);
  }
  // D: row = q*4 + r, col = ml (per verified gfx950 C/D mapping)
#pragma unroll
  for (int r = 0; r < 4; ++r) {
    int mr = mt * 16 + q * 4 + r;
    if (mr < N_ITEM) {
      float* dst = xfc + (size_t)mr * 64 + ml;
      atomicAdd(dst +  0, acc0[r]);
      atomicAdd(dst + 16, acc1[r]);
      atomicAdd(dst + 32, acc2[r]);
      atomicAdd(dst + 48, acc3[r]);
    }
  }
}

// ---------------- per-group, per-column batch norm (ddof=1) ----------------
__global__ __launch_bounds__(256) void k_norm(
    const float* __restrict__ xfc, float* __restrict__ item) {
  __shared__ float red[256];
  int grp = blockIdx.x >> 6;
  int o = blockIdx.x & 63;
  int base = grp ? N_CELL : 0;
  int N = grp ? N_DRUG : N_CELL;
  int tid = threadIdx.x;
  float s = 0.f;
  for (int i = tid; i < N; i += 256) s += xfc[(size_t)(base + i) * 64 + o];
  red[tid] = s; __syncthreads();
  for (int w = 128; w > 0; w >>= 1) { if (tid < w) red[tid] += red[tid + w]; __syncthreads(); }
  float mean = red[0] / (float)N;
  __syncthreads();
  float sq = 0.f;
  for (int i = tid; i < N; i += 256) {
    float d = xfc[(size_t)(base + i) * 64 + o] - mean;
    sq += d * d;
  }
  red[tid] = sq; __syncthreads();
  for (int w = 128; w > 0; w >>= 1) { if (tid < w) red[tid] += red[tid + w]; __syncthreads(); }
  float inv_std = 1.f / sqrtf(red[0] / (float)(N - 1));
  for (int i = tid; i < N; i += 256)
    item[(size_t)(base + i) * 64 + o] = (xfc[(size_t)(base + i) * 64 + o] - mean) * inv_std;
}

// ---------------- interact (2-hop attention) + agg GEMV ----------------
__global__ __launch_bounds__(256) void k_interact(
    const int* __restrict__ cell_nbr, const int* __restrict__ drug_nbr,
    const float* __restrict__ protein, const float* __restrict__ item,
    const float* __restrict__ agg_w, const float* __restrict__ agg_b,
    float* __restrict__ emb) {
  __shared__ float pb[128 * 65];
  __shared__ float item_s[64];
  __shared__ float sc[128];
  __shared__ float hop_out[128];
  __shared__ float red[256];
  int n = blockIdx.x;
  int tid = threadIdx.x;
  const int* nbr = (n < N_CELL) ? (cell_nbr + (size_t)n * 256)
                                : (drug_nbr + (size_t)(n - N_CELL) * 256);
  if (tid < 64) item_s[tid] = item[(size_t)n * 64 + tid];
  __syncthreads();
  for (int h = 0; h < 2; ++h) {
    for (int e = tid; e < 8192; e += 256) {
      int k = e >> 6, d = e & 63;
      int idx = nbr[h * 128 + k];
      pb[k * 65 + d] = protein[(size_t)idx * 64 + d];
    }
    __syncthreads();
    {
      int k = tid >> 1, halfd = tid & 1;
      int d0 = halfd * 32;
      float p = 0.f;
#pragma unroll
      for (int d = 0; d < 32; ++d) p += item_s[d0 + d] * pb[k * 65 + d0 + d];
      p += __shfl_xor(p, 1);
      if (halfd == 0) sc[k] = p;
    }
    __syncthreads();
    if (tid < 64) {
      float a = sc[tid], b = sc[tid + 64];
      float m = fmaxf(a, b);
#pragma unroll
      for (int off = 32; off > 0; off >>= 1) m = fmaxf(m, __shfl_xor(m, off));
      float e0 = __expf(a - m), e1 = __expf(b - m);
      float s = e0 + e1;
#pragma unroll
      for (int off = 32; off > 0; off >>= 1) s += __shfl_xor(s, off);
      float inv = 1.f / s;
      sc[tid] = e0 * inv; sc[tid + 64] = e1 * inv;
    }
    __syncthreads();
    {
      int d = tid & 63, kq = tid >> 6;
      float p = 0.f;
#pragma unroll
      for (int k = 0; k < 32; ++k) {
        int kk = kq * 32 + k;
        p += sc[kk] * pb[kk * 65 + d];
      }
      red[tid] = p;
    }
    __syncthreads();
    if (tid < 64)
      hop_out[h * 64 + tid] = red[tid] + red[tid + 64] + red[tid + 128] + red[tid + 192];
    __syncthreads();
  }
  {
    int o = tid & 63, jq = tid >> 6;
    float p = 0.f;
#pragma unroll
    for (int j = 0; j < 32; ++j) {
      int jj = jq * 32 + j;
      p += hop_out[jj] * agg_w[(size_t)o * 128 + jj];
    }
    red[tid] = p;
  }
  __syncthreads();
  if (tid < 64)
    emb[(size_t)n * 64 + tid] =
        red[tid] + red[tid + 64] + red[tid + 128] + red[tid + 192] + agg_b[tid];
}

// ---------------- final scoring, one wave per batch row ----------------
__global__ __launch_bounds__(256) void k_score(
    const int* __restrict__ data, const float* __restrict__ emb,
    const float* __restrict__ comb_w, float* __restrict__ out,
    float* __restrict__ loss) {
  __shared__ float racc[4];
  int tid = threadIdx.x;
  int lane = tid & 63;
  int w = tid >> 6;
  int b = blockIdx.x * 4 + w;
  int c = data[b * 3 + 0], d1 = data[b * 3 + 1], d2 = data[b * 3 + 2];
  float ce = emb[(size_t)c * 64 + lane];
  float e1 = emb[(size_t)(N_CELL + d1) * 64 + lane];
  float e2 = emb[(size_t)(N_CELL + d2) * 64 + lane];
  const float4* wrow = (const float4*)(comb_w + (size_t)lane * 128);
  float comb = 0.f;
#pragma unroll
  for (int j4 = 0; j4 < 16; ++j4) {
    float4 w4 = wrow[j4];
    int j = j4 * 4;
    comb += __shfl(e1, j) * w4.x + __shfl(e1, j + 1) * w4.y +
            __shfl(e1, j + 2) * w4.z + __shfl(e1, j + 3) * w4.w;
  }
#pragma unroll
  for (int j4 = 16; j4 < 32; ++j4) {
    float4 w4 = wrow[j4];
    int j = j4 * 4 - 64;
    comb += __shfl(e2, j) * w4.x + __shfl(e2, j + 1) * w4.y +
            __shfl(e2, j + 2) * w4.z + __shfl(e2, j + 3) * w4.w;
  }
  float th = comb * ce;
  float tx = e1 * e2;
  float rg = ce * ce + e1 * e1 + e2 * e2;
#pragma unroll
  for (int off = 32; off > 0; off >>= 1) {
    th += __shfl_xor(th, off);
    tx += __shfl_xor(tx, off);
    rg += __shfl_xor(rg, off);
  }
  if (lane == 0) { out[b] = th - tx; racc[w] = rg; }
  __syncthreads();
  if (tid == 0) atomicAdd(loss, 0.5f * (racc[0] + racc[1] + racc[2] + racc[3]));
}

// ---------------- node regularization (6 gathered rows) ----------------
__global__ __launch_bounds__(256) void k_nodereg(
    const int* __restrict__ data, const int* __restrict__ cell_nbr,
    const int* __restrict__ drug_nbr, const float* __restrict__ protein,
    float* __restrict__ loss) {
  __shared__ float red[256];
  int j = blockIdx.x;  // 0..5
  int hop = j / 3, which = j % 3;
  int row = data[hop * 3 + which];
  const int* nbr = (which == 0) ? (cell_nbr + (size_t)row * 256)
                                : (drug_nbr + (size_t)row * 256);
  int tid = threadIdx.x;
  float acc = 0.f;
  for (int e = tid; e < 16384; e += 256) {
    int k = e >> 6, d = e & 63;
    float v = protein[(size_t)nbr[k] * 64 + d];
    acc += v * v;
  }
  red[tid] = acc; __syncthreads();
  for (int w = 128; w > 0; w >>= 1) { if (tid < w) red[tid] += red[tid + w]; __syncthreads(); }
  if (tid == 0) atomicAdd(loss, 0.5f * red[0]);
}

__global__ void k_finalize(const float* __restrict__ loss, float* __restrict__ out) {
  if (threadIdx.x == 0) out[BATCH] = loss[0] * (1e-6f / 4096.f);
}

extern "C" void kernel_launch(void* const* d_in, const int* in_sizes, int n_in,
                              void* d_out, int out_size, void* d_ws, size_t ws_size,
                              hipStream_t stream) {
  const int*   data      = (const int*)d_in[0];
  const int*   cell_nbr  = (const int*)d_in[1];
  const int*   drug_nbr  = (const int*)d_in[2];
  const float* protein   = (const float*)d_in[3];
  const float* cell_pre  = (const float*)d_in[4];
  const float* drug_pre  = (const float*)d_in[5];
  const float* w1        = (const float*)d_in[6];
  const float* b1        = (const float*)d_in[7];
  const float* w2        = (const float*)d_in[8];
  const float* b2        = (const float*)d_in[9];
  const float* out_w     = (const float*)d_in[10];
  const float* agg_w     = (const float*)d_in[12];
  const float* agg_b     = (const float*)d_in[13];
  const float* comb_w    = (const float*)d_in[14];
  float* out = (float*)d_out;
  char* base = (char*)d_ws;
  float* pool1            = (float*)base;
  unsigned short* pool2   = (unsigned short*)(base + POOL2_B);
  unsigned short* wbf     = (unsigned short*)(base + WBF_B);
  float* xfc              = (float*)(base + XFC_B);
  float* item             = (float*)(base + ITEM_B);
  float* emb              = (float*)(base + EMB_B);
  float* loss             = (float*)(base + LOSS_B);

  k_cast<<<512, 256, 0, stream>>>(out_w, wbf, xfc);
  k_conv1<<<dim3(2, 840), 256, 0, stream>>>(cell_pre, drug_pre, w1, b1, pool1, loss);
  k_conv2<<<dim3(2, 840), 256, 0, stream>>>(pool1, w2, b2, pool2);
  k_fc<<<dim3(53, 32), 64, 0, stream>>>(pool2, wbf, xfc);
  k_norm<<<128, 256, 0, stream>>>(xfc, item);
  k_interact<<<840, 256, 0, stream>>>(cell_nbr, drug_nbr, protein, item, agg_w, agg_b, emb);
  k_score<<<1024, 256, 0, stream>>>(data, emb, comb_w, out, loss);
  k_nodereg<<<6, 256, 0, stream>>>(data, cell_nbr, drug_nbr, protein, loss);
  k_finalize<<<1, 64, 0, stream>>>(loss, out);
}

// Round 4
// 303.014 us; speedup vs baseline: 1.2622x; 1.2622x over previous
//
#include <hip/hip_runtime.h>
#include <hip/hip_bf16.h>
#include <math.h>

#define N_CELL 76
#define N_DRUG 764
#define N_ITEM 840
#define BATCH  4096

// ws layout (byte offsets)
// Phase A (convs): pool1 f32 [840][64][64][4] : 0 .. 55,050,240
//                  pool2h bf16 [840][8192]    : 55,050,240 .. 68,812,800
//                  pool2l bf16 [840][8192]    : 68,812,800 .. 82,575,360
// Phase B (after conv2, aliases dead pool1):
//                  whi bf16 [64][8192] : 0 .. 1,048,576
//                  wlo bf16 [64][8192] : 1,048,576 .. 2,097,152
//                  xfc f32 [840][64]   : 2,097,152 .. 2,312,192
//                  item f32 [840][64]  : 2,312,192 .. 2,527,232
//                  emb f32 [840][64]   : 2,527,232 .. 2,742,272
//                  V f32 [76][128]     : 2,742,272 .. 2,781,184
//                  loss f32            : 2,781,184
#define POOL2H_B 55050240u
#define POOL2L_B 68812800u
#define WHI_B    0u
#define WLO_B    1048576u
#define XFC_B    2097152u
#define ITEM_B   2312192u
#define EMB_B    2527232u
#define V_B      2742272u
#define LOSS_B   2781184u

typedef short bh8 __attribute__((ext_vector_type(8)));
typedef float f32x4 __attribute__((ext_vector_type(4)));

static __device__ inline unsigned short f2bf(float f) {
  union { float f; unsigned u; } v; v.f = f;
  unsigned r = v.u + 0x7FFFu + ((v.u >> 16) & 1u);  // RNE (no NaN inputs here)
  return (unsigned short)(r >> 16);
}
static __device__ inline float bf2f(unsigned short h) {
  union { unsigned u; float f; } v; v.u = ((unsigned)h) << 16;
  return v.f;
}

// ---------------- conv1 (1->4ch, 3x3 SAME) + relu + maxpool2 ----------------
// grid (2, 840). Thread: 4 conv cols (aligned b128 LDS read, halo via shfl),
// 2 conv rows -> 2 pool px intra-thread. Writes pool1 interleaved [py][px][4c].
// NOTE: no min-occupancy launch bound — a forced VGPR cap caused spills (R3).
__global__ __launch_bounds__(256) void k_conv1(
    const float* __restrict__ cell_pre, const float* __restrict__ drug_pre,
    const float* __restrict__ w1, const float* __restrict__ b1,
    float* __restrict__ pool1) {
  __shared__ float img[66 * 128];
  int half = blockIdx.x, n = blockIdx.y;
  int tid = threadIdx.x;
  int cy0 = half * 64;
  const float* src = (n < N_CELL) ? (cell_pre + (size_t)n * 16384)
                                  : (drug_pre + (size_t)(n - N_CELL) * 16384);
  for (int i = tid; i < 66 * 32; i += 256) {
    int r = i >> 5, c = i & 31;
    int iy = cy0 - 1 + r;
    float4 v = make_float4(0.f, 0.f, 0.f, 0.f);
    if (iy >= 0 && iy < 128) v = ((const float4*)src)[iy * 32 + c];
    ((float4*)img)[i] = v;
  }
  float wv[4][9], bb[4];
#pragma unroll
  for (int c = 0; c < 4; ++c) {
    bb[c] = b1[c];
#pragma unroll
    for (int j = 0; j < 9; ++j) wv[c][j] = w1[c * 9 + j];
  }
  __syncthreads();
  int t = tid & 31;   // col group: conv cols 4t..4t+3
  int g = tid >> 5;   // 0..7 row groups
  const float4* img4 = (const float4*)img;
#pragma unroll 1
  for (int rpi = 0; rpi < 4; ++rpi) {
    int rp = g + 8 * rpi;  // local pool row 0..31
    int ly = 2 * rp;
    float4 rowv[4]; float lo[4], hi[4];
#pragma unroll
    for (int rr = 0; rr < 4; ++rr) {
      rowv[rr] = img4[(ly + rr) * 32 + t];
      float l = __shfl_up(rowv[rr].w, 1);
      float h = __shfl_down(rowv[rr].x, 1);
      lo[rr] = (t == 0) ? 0.f : l;
      hi[rr] = (t == 31) ? 0.f : h;
    }
    float a[2][4][4];
#pragma unroll
    for (int orow = 0; orow < 2; ++orow)
#pragma unroll
      for (int oc = 0; oc < 4; ++oc)
#pragma unroll
        for (int c = 0; c < 4; ++c) a[orow][oc][c] = bb[oc];
#pragma unroll
    for (int orow = 0; orow < 2; ++orow) {
#pragma unroll
      for (int kr = 0; kr < 3; ++kr) {
        int rr = orow + kr;
        float in[6] = {lo[rr], rowv[rr].x, rowv[rr].y, rowv[rr].z, rowv[rr].w, hi[rr]};
#pragma unroll
        for (int ks = 0; ks < 3; ++ks)
#pragma unroll
          for (int oc = 0; oc < 4; ++oc) {
            float w = wv[oc][kr * 3 + ks];
#pragma unroll
            for (int c = 0; c < 4; ++c) a[orow][oc][c] += in[c + ks] * w;
          }
      }
    }
#pragma unroll
    for (int pc = 0; pc < 2; ++pc) {
      float4 res;
      float* resf = (float*)&res;
#pragma unroll
      for (int oc = 0; oc < 4; ++oc) {
        float m = fmaxf(fmaxf(a[0][oc][2 * pc], a[0][oc][2 * pc + 1]),
                        fmaxf(a[1][oc][2 * pc], a[1][oc][2 * pc + 1]));
        resf[oc] = fmaxf(m, 0.f);
      }
      int py = half * 32 + rp, px = 2 * t + pc;
      ((float4*)pool1)[((size_t)n * 64 + py) * 64 + px] = res;
    }
  }
}

// ---------------- conv2 (4->8ch, 3x3 SAME) + relu + maxpool2 -> split bf16 ----------------
// grid (2, 840). One row-pair at a time: 16 live accs (no spill), weights via
// uniform s_loads, zero-padded LDS borders, b128 reads only.
__global__ __launch_bounds__(256) void k_conv2(
    const float* __restrict__ pool1, const float* __restrict__ w2,
    const float* __restrict__ b2, unsigned short* __restrict__ pool2h,
    unsigned short* __restrict__ pool2l) {
  __shared__ float p1[34 * 66 * 4];  // [row][col 0..65][4ch]; col0/col65 zero
  int half = blockIdx.x, n = blockIdx.y;
  int tid = threadIdx.x;
  int cy0 = half * 32;
  const float4* src = (const float4*)(pool1 + (size_t)n * 16384);
  for (int i = tid; i < 34 * 64; i += 256) {
    int r = i >> 6, c = i & 63;
    int iy = cy0 - 1 + r;
    float4 v = make_float4(0.f, 0.f, 0.f, 0.f);
    if (iy >= 0 && iy < 64) v = src[iy * 64 + c];
    ((float4*)p1)[r * 66 + c + 1] = v;
  }
  if (tid < 68) {
    int r = tid >> 1, c = (tid & 1) ? 65 : 0;
    ((float4*)p1)[r * 66 + c] = make_float4(0.f, 0.f, 0.f, 0.f);
  }
  float bb[8];
#pragma unroll
  for (int o = 0; o < 8; ++o) bb[o] = b2[o];
  __syncthreads();
  int x = tid & 63;  // conv column
  int w = tid >> 6;  // wave -> pool rows w, w+4, w+8, w+12
  const float4* p14 = (const float4*)p1;
#pragma unroll 1
  for (int rpi = 0; rpi < 4; ++rpi) {
    int rp = w + 4 * rpi;
    float acc[2][8];
#pragma unroll
    for (int rr = 0; rr < 2; ++rr)
#pragma unroll
      for (int oc = 0; oc < 8; ++oc) acc[rr][oc] = bb[oc];
#pragma unroll
    for (int kr = 0; kr < 3; ++kr) {
#pragma unroll
      for (int ks = 0; ks < 3; ++ks) {
        float4 v0 = p14[(2 * rp + kr) * 66 + x + ks];
        float4 v1 = p14[(2 * rp + 1 + kr) * 66 + x + ks];
#pragma unroll
        for (int oc = 0; oc < 8; ++oc) {
          float w0 = w2[(oc * 4 + 0) * 9 + kr * 3 + ks];
          float w1_ = w2[(oc * 4 + 1) * 9 + kr * 3 + ks];
          float w2_ = w2[(oc * 4 + 2) * 9 + kr * 3 + ks];
          float w3 = w2[(oc * 4 + 3) * 9 + kr * 3 + ks];
          acc[0][oc] += v0.x * w0 + v0.y * w1_ + v0.z * w2_ + v0.w * w3;
          acc[1][oc] += v1.x * w0 + v1.y * w1_ + v1.z * w2_ + v1.w * w3;
        }
      }
    }
    int py = half * 16 + rp, px = x >> 1;
#pragma unroll
    for (int oc = 0; oc < 8; ++oc) {
      float m = fmaxf(fmaxf(acc[0][oc], acc[1][oc]), 0.f);
      m = fmaxf(m, __shfl_xor(m, 1));
      if ((x & 1) == 0) {
        size_t idx = (size_t)n * 8192 + oc * 1024 + py * 32 + px;
        unsigned short mh = f2bf(m);
        pool2h[idx] = mh;
        pool2l[idx] = f2bf(m - bf2f(mh));
      }
    }
  }
}

// ---------------- cast out_w -> split bf16; zero xfc & loss ----------------
// Runs AFTER conv2 (whi/wlo/xfc/loss alias the dead pool1 region).
__global__ __launch_bounds__(256) void k_cast(
    const float* __restrict__ out_w, unsigned short* __restrict__ whi,
    unsigned short* __restrict__ wlo, float* __restrict__ xfc,
    float* __restrict__ loss) {
  int gid = blockIdx.x * 256 + threadIdx.x;  // 131072 = 524288/4
  if (gid == 0) *loss = 0.f;
  float4 v = ((const float4*)out_w)[gid];
  ushort4 h, l;
  h.x = f2bf(v.x); l.x = f2bf(v.x - bf2f(h.x));
  h.y = f2bf(v.y); l.y = f2bf(v.y - bf2f(h.y));
  h.z = f2bf(v.z); l.z = f2bf(v.z - bf2f(h.z));
  h.w = f2bf(v.w); l.w = f2bf(v.w - bf2f(h.w));
  ((ushort4*)whi)[gid] = h;
  ((ushort4*)wlo)[gid] = l;
  if (gid < N_ITEM * 64) xfc[gid] = 0.f;
}

// ---------------- FC: split-bf16 MFMA GEMM, M=840 N=64, K chunks of 256 ----------------
// grid (53 M-tiles, 32 K-chunks), 1 wave. acc = ah*bh + ah*bl + al*bh (fp32-class).
// out_b omitted: cancels exactly in the per-column batch norm.
__global__ __launch_bounds__(64) void k_fc(
    const unsigned short* __restrict__ pool2h, const unsigned short* __restrict__ pool2l,
    const unsigned short* __restrict__ whi, const unsigned short* __restrict__ wlo,
    float* __restrict__ xfc) {
  int mt = blockIdx.x, kc = blockIdx.y;
  int lane = threadIdx.x;
  int ml = lane & 15, q = lane >> 4;
  int row = mt * 16 + ml; if (row > N_ITEM - 1) row = N_ITEM - 1;  // clamp (stores guarded)
  size_t k0 = (size_t)kc * 256 + q * 8;
  const bh8* Ah = (const bh8*)(pool2h + (size_t)row * 8192 + k0);
  const bh8* Al = (const bh8*)(pool2l + (size_t)row * 8192 + k0);
  const bh8* Bh[4], * Bl[4];
#pragma unroll
  for (int nb = 0; nb < 4; ++nb) {
    Bh[nb] = (const bh8*)(whi + (size_t)(nb * 16 + ml) * 8192 + k0);
    Bl[nb] = (const bh8*)(wlo + (size_t)(nb * 16 + ml) * 8192 + k0);
  }
  f32x4 acc[4];
#pragma unroll
  for (int nb = 0; nb < 4; ++nb) acc[nb] = (f32x4){0.f, 0.f, 0.f, 0.f};
#pragma unroll
  for (int st = 0; st < 8; ++st) {
    bh8 ah = Ah[st * 4], al = Al[st * 4];
#pragma unroll
    for (int nb = 0; nb < 4; ++nb) {
      bh8 bhv = Bh[nb][st * 4], blv = Bl[nb][st * 4];
      acc[nb] = __builtin_amdgcn_mfma_f32_16x16x32_bf16(ah, bhv, acc[nb], 0, 0, 0);
      acc[nb] = __builtin_amdgcn_mfma_f32_16x16x32_bf16(ah, blv, acc[nb], 0, 0, 0);
      acc[nb] = __builtin_amdgcn_mfma_f32_16x16x32_bf16(al, bhv, acc[nb], 0, 0, 0);
    }
  }
#pragma unroll
  for (int r = 0; r < 4; ++r) {
    int mr = mt * 16 + q * 4 + r;
    if (mr < N_ITEM) {
      float* dst = xfc + (size_t)mr * 64 + ml;
#pragma unroll
      for (int nb = 0; nb < 4; ++nb) atomicAdd(dst + nb * 16, acc[nb][r]);
    }
  }
}

// ---------------- per-group, per-column batch norm (ddof=1) ----------------
__global__ __launch_bounds__(256) void k_norm(
    const float* __restrict__ xfc, float* __restrict__ item) {
  __shared__ float red[256];
  int grp = blockIdx.x >> 6;
  int o = blockIdx.x & 63;
  int base = grp ? N_CELL : 0;
  int N = grp ? N_DRUG : N_CELL;
  int tid = threadIdx.x;
  float s = 0.f;
  for (int i = tid; i < N; i += 256) s += xfc[(size_t)(base + i) * 64 + o];
  red[tid] = s; __syncthreads();
  for (int w = 128; w > 0; w >>= 1) { if (tid < w) red[tid] += red[tid + w]; __syncthreads(); }
  float mean = red[0] / (float)N;
  __syncthreads();
  float sq = 0.f;
  for (int i = tid; i < N; i += 256) {
    float d = xfc[(size_t)(base + i) * 64 + o] - mean;
    sq += d * d;
  }
  red[tid] = sq; __syncthreads();
  for (int w = 128; w > 0; w >>= 1) { if (tid < w) red[tid] += red[tid + w]; __syncthreads(); }
  float inv_std = 1.f / sqrtf(red[0] / (float)(N - 1));
  for (int i = tid; i < N; i += 256)
    item[(size_t)(base + i) * 64 + o] = (xfc[(size_t)(base + i) * 64 + o] - mean) * inv_std;
}

// ---------------- interact (2-hop attention) + agg GEMV ----------------
__global__ __launch_bounds__(256) void k_interact(
    const int* __restrict__ cell_nbr, const int* __restrict__ drug_nbr,
    const float* __restrict__ protein, const float* __restrict__ item,
    const float* __restrict__ agg_w, const float* __restrict__ agg_b,
    float* __restrict__ emb) {
  __shared__ float pb[128 * 65];
  __shared__ float item_s[64];
  __shared__ float sc[128];
  __shared__ float hop_out[128];
  __shared__ float red[256];
  int n = blockIdx.x;
  int tid = threadIdx.x;
  const int* nbr = (n < N_CELL) ? (cell_nbr + (size_t)n * 256)
                                : (drug_nbr + (size_t)(n - N_CELL) * 256);
  if (tid < 64) item_s[tid] = item[(size_t)n * 64 + tid];
  __syncthreads();
  for (int h = 0; h < 2; ++h) {
    for (int e = tid; e < 8192; e += 256) {
      int k = e >> 6, d = e & 63;
      int idx = nbr[h * 128 + k];
      pb[k * 65 + d] = protein[(size_t)idx * 64 + d];
    }
    __syncthreads();
    {
      int k = tid >> 1, halfd = tid & 1;
      int d0 = halfd * 32;
      float p = 0.f;
#pragma unroll
      for (int d = 0; d < 32; ++d) p += item_s[d0 + d] * pb[k * 65 + d0 + d];
      p += __shfl_xor(p, 1);
      if (halfd == 0) sc[k] = p;
    }
    __syncthreads();
    if (tid < 64) {
      float a = sc[tid], b = sc[tid + 64];
      float m = fmaxf(a, b);
#pragma unroll
      for (int off = 32; off > 0; off >>= 1) m = fmaxf(m, __shfl_xor(m, off));
      float e0 = __expf(a - m), e1 = __expf(b - m);
      float s = e0 + e1;
#pragma unroll
      for (int off = 32; off > 0; off >>= 1) s += __shfl_xor(s, off);
      float inv = 1.f / s;
      sc[tid] = e0 * inv; sc[tid + 64] = e1 * inv;
    }
    __syncthreads();
    {
      int d = tid & 63, kq = tid >> 6;
      float p = 0.f;
#pragma unroll
      for (int k = 0; k < 32; ++k) {
        int kk = kq * 32 + k;
        p += sc[kk] * pb[kk * 65 + d];
      }
      red[tid] = p;
    }
    __syncthreads();
    if (tid < 64)
      hop_out[h * 64 + tid] = red[tid] + red[tid + 64] + red[tid + 128] + red[tid + 192];
    __syncthreads();
  }
  {
    int o = tid & 63, jq = tid >> 6;
    float p = 0.f;
#pragma unroll
    for (int j = 0; j < 32; ++j) {
      int jj = jq * 32 + j;
      p += hop_out[jj] * agg_w[(size_t)o * 128 + jj];
    }
    red[tid] = p;
  }
  __syncthreads();
  if (tid < 64)
    emb[(size_t)n * 64 + tid] =
        red[tid] + red[tid + 64] + red[tid + 128] + red[tid + 192] + agg_b[tid];
}

// ---------------- precompute V[c] = comb_w^T @ cell_emb[c]  (76 x 128) ----------------
__global__ __launch_bounds__(128) void k_cellv(
    const float* __restrict__ emb, const float* __restrict__ comb_w,
    float* __restrict__ V) {
  __shared__ float ce[64];
  int c = blockIdx.x;
  int j = threadIdx.x;
  if (j < 64) ce[j] = emb[(size_t)c * 64 + j];
  __syncthreads();
  float s = 0.f;
#pragma unroll
  for (int o = 0; o < 64; ++o) s += comb_w[(size_t)o * 128 + j] * ce[o];
  V[(size_t)c * 128 + j] = s;
}

// ---------------- final scoring: therapy = cat(e1,e2) . V[c], toxic = e1.e2 ----------------
__global__ __launch_bounds__(256) void k_score(
    const int* __restrict__ data, const float* __restrict__ emb,
    const float* __restrict__ V, float* __restrict__ out,
    float* __restrict__ loss) {
  __shared__ float racc[4];
  int tid = threadIdx.x;
  int lane = tid & 63;
  int w = tid >> 6;
  int b = blockIdx.x * 4 + w;
  int c = data[b * 3 + 0], d1 = data[b * 3 + 1], d2 = data[b * 3 + 2];
  float ce = emb[(size_t)c * 64 + lane];
  float e1 = emb[(size_t)(N_CELL + d1) * 64 + lane];
  float e2 = emb[(size_t)(N_CELL + d2) * 64 + lane];
  float v1 = V[(size_t)c * 128 + lane];
  float v2 = V[(size_t)c * 128 + 64 + lane];
  float th = e1 * v1 + e2 * v2;
  float tx = e1 * e2;
  float rg = ce * ce + e1 * e1 + e2 * e2;
#pragma unroll
  for (int off = 32; off > 0; off >>= 1) {
    th += __shfl_xor(th, off);
    tx += __shfl_xor(tx, off);
    rg += __shfl_xor(rg, off);
  }
  if (lane == 0) { out[b] = th - tx; racc[w] = rg; }
  __syncthreads();
  if (tid == 0) atomicAdd(loss, 0.5f * (racc[0] + racc[1] + racc[2] + racc[3]));
}

// ---------------- node regularization (6 gathered rows) ----------------
__global__ __launch_bounds__(256) void k_nodereg(
    const int* __restrict__ data, const int* __restrict__ cell_nbr,
    const int* __restrict__ drug_nbr, const float* __restrict__ protein,
    float* __restrict__ loss) {
  __shared__ float red[256];
  int j = blockIdx.x;  // 0..5
  int hop = j / 3, which = j % 3;
  int row = data[hop * 3 + which];
  const int* nbr = (which == 0) ? (cell_nbr + (size_t)row * 256)
                                : (drug_nbr + (size_t)row * 256);
  int tid = threadIdx.x;
  float acc = 0.f;
  for (int e = tid; e < 16384; e += 256) {
    int k = e >> 6, d = e & 63;
    float v = protein[(size_t)nbr[k] * 64 + d];
    acc += v * v;
  }
  red[tid] = acc; __syncthreads();
  for (int w = 128; w > 0; w >>= 1) { if (tid < w) red[tid] += red[tid + w]; __syncthreads(); }
  if (tid == 0) atomicAdd(loss, 0.5f * red[0]);
}

__global__ void k_finalize(const float* __restrict__ loss, float* __restrict__ out) {
  if (threadIdx.x == 0) out[BATCH] = loss[0] * (1e-6f / 4096.f);
}

extern "C" void kernel_launch(void* const* d_in, const int* in_sizes, int n_in,
                              void* d_out, int out_size, void* d_ws, size_t ws_size,
                              hipStream_t stream) {
  const int*   data      = (const int*)d_in[0];
  const int*   cell_nbr  = (const int*)d_in[1];
  const int*   drug_nbr  = (const int*)d_in[2];
  const float* protein   = (const float*)d_in[3];
  const float* cell_pre  = (const float*)d_in[4];
  const float* drug_pre  = (const float*)d_in[5];
  const float* w1        = (const float*)d_in[6];
  const float* b1        = (const float*)d_in[7];
  const float* w2        = (const float*)d_in[8];
  const float* b2        = (const float*)d_in[9];
  const float* out_w     = (const float*)d_in[10];
  const float* agg_w     = (const float*)d_in[12];
  const float* agg_b     = (const float*)d_in[13];
  const float* comb_w    = (const float*)d_in[14];
  float* out = (float*)d_out;
  char* base = (char*)d_ws;
  float* pool1            = (float*)base;
  unsigned short* pool2h  = (unsigned short*)(base + POOL2H_B);
  unsigned short* pool2l  = (unsigned short*)(base + POOL2L_B);
  unsigned short* whi     = (unsigned short*)(base + WHI_B);
  unsigned short* wlo     = (unsigned short*)(base + WLO_B);
  float* xfc              = (float*)(base + XFC_B);
  float* item             = (float*)(base + ITEM_B);
  float* emb              = (float*)(base + EMB_B);
  float* V                = (float*)(base + V_B);
  float* loss             = (float*)(base + LOSS_B);

  k_conv1<<<dim3(2, 840), 256, 0, stream>>>(cell_pre, drug_pre, w1, b1, pool1);
  k_conv2<<<dim3(2, 840), 256, 0, stream>>>(pool1, w2, b2, pool2h, pool2l);
  k_cast<<<512, 256, 0, stream>>>(out_w, whi, wlo, xfc, loss);
  k_fc<<<dim3(53, 32), 64, 0, stream>>>(pool2h, pool2l, whi, wlo, xfc);
  k_norm<<<128, 256, 0, stream>>>(xfc, item);
  k_interact<<<840, 256, 0, stream>>>(cell_nbr, drug_nbr, protein, item, agg_w, agg_b, emb);
  k_cellv<<<N_CELL, 128, 0, stream>>>(emb, comb_w, V);
  k_score<<<1024, 256, 0, stream>>>(data, emb, V, out, loss);
  k_nodereg<<<6, 256, 0, stream>>>(data, cell_nbr, drug_nbr, protein, loss);
  k_finalize<<<1, 64, 0, stream>>>(loss, out);
}

// Round 5
// 301.893 us; speedup vs baseline: 1.2668x; 1.0037x over previous
//
#include <hip/hip_runtime.h>
#include <hip/hip_bf16.h>
#include <math.h>

#define N_CELL 76
#define N_DRUG 764
#define N_ITEM 840
#define BATCH  4096

// ws layout (byte offsets)
// Phase A (convs): pool1 f32 [840][64][64][4] : 0 .. 55,050,240
//                  pool2h bf16 [840][8192]    : 55,050,240 .. 68,812,800
//                  pool2l bf16 [840][8192]    : 68,812,800 .. 82,575,360
// Phase B (after conv2, aliases dead pool1):
//                  whi bf16 [64][8192], wlo, xfc, item, emb, V, loss
#define POOL2H_B 55050240u
#define POOL2L_B 68812800u
#define WHI_B    0u
#define WLO_B    1048576u
#define XFC_B    2097152u
#define ITEM_B   2312192u
#define EMB_B    2527232u
#define V_B      2742272u
#define LOSS_B   2781184u

typedef short bh8 __attribute__((ext_vector_type(8)));
typedef float f32x4 __attribute__((ext_vector_type(4)));

static __device__ inline unsigned short f2bf(float f) {
  union { float f; unsigned u; } v; v.f = f;
  unsigned r = v.u + 0x7FFFu + ((v.u >> 16) & 1u);  // RNE (no NaN inputs here)
  return (unsigned short)(r >> 16);
}
static __device__ inline float bf2f(unsigned short h) {
  union { unsigned u; float f; } v; v.u = ((unsigned)h) << 16;
  return v.f;
}

// ---------------- conv1 (1->4ch, 3x3 SAME) + relu + maxpool2 ----------------
// (unchanged from R4 — isolating the conv2 delta this round)
__global__ __launch_bounds__(256) void k_conv1(
    const float* __restrict__ cell_pre, const float* __restrict__ drug_pre,
    const float* __restrict__ w1, const float* __restrict__ b1,
    float* __restrict__ pool1) {
  __shared__ float img[66 * 128];
  int half = blockIdx.x, n = blockIdx.y;
  int tid = threadIdx.x;
  int cy0 = half * 64;
  const float* src = (n < N_CELL) ? (cell_pre + (size_t)n * 16384)
                                  : (drug_pre + (size_t)(n - N_CELL) * 16384);
  for (int i = tid; i < 66 * 32; i += 256) {
    int r = i >> 5, c = i & 31;
    int iy = cy0 - 1 + r;
    float4 v = make_float4(0.f, 0.f, 0.f, 0.f);
    if (iy >= 0 && iy < 128) v = ((const float4*)src)[iy * 32 + c];
    ((float4*)img)[i] = v;
  }
  float wv[4][9], bb[4];
#pragma unroll
  for (int c = 0; c < 4; ++c) {
    bb[c] = b1[c];
#pragma unroll
    for (int j = 0; j < 9; ++j) wv[c][j] = w1[c * 9 + j];
  }
  __syncthreads();
  int t = tid & 31;
  int g = tid >> 5;
  const float4* img4 = (const float4*)img;
#pragma unroll 1
  for (int rpi = 0; rpi < 4; ++rpi) {
    int rp = g + 8 * rpi;
    int ly = 2 * rp;
    float4 rowv[4]; float lo[4], hi[4];
#pragma unroll
    for (int rr = 0; rr < 4; ++rr) {
      rowv[rr] = img4[(ly + rr) * 32 + t];
      float l = __shfl_up(rowv[rr].w, 1);
      float h = __shfl_down(rowv[rr].x, 1);
      lo[rr] = (t == 0) ? 0.f : l;
      hi[rr] = (t == 31) ? 0.f : h;
    }
    float a[2][4][4];
#pragma unroll
    for (int orow = 0; orow < 2; ++orow)
#pragma unroll
      for (int oc = 0; oc < 4; ++oc)
#pragma unroll
        for (int c = 0; c < 4; ++c) a[orow][oc][c] = bb[oc];
#pragma unroll
    for (int orow = 0; orow < 2; ++orow) {
#pragma unroll
      for (int kr = 0; kr < 3; ++kr) {
        int rr = orow + kr;
        float in[6] = {lo[rr], rowv[rr].x, rowv[rr].y, rowv[rr].z, rowv[rr].w, hi[rr]};
#pragma unroll
        for (int ks = 0; ks < 3; ++ks)
#pragma unroll
          for (int oc = 0; oc < 4; ++oc) {
            float w = wv[oc][kr * 3 + ks];
#pragma unroll
            for (int c = 0; c < 4; ++c) a[orow][oc][c] += in[c + ks] * w;
          }
      }
    }
#pragma unroll
    for (int pc = 0; pc < 2; ++pc) {
      float4 res;
      float* resf = (float*)&res;
#pragma unroll
      for (int oc = 0; oc < 4; ++oc) {
        float m = fmaxf(fmaxf(a[0][oc][2 * pc], a[0][oc][2 * pc + 1]),
                        fmaxf(a[1][oc][2 * pc], a[1][oc][2 * pc + 1]));
        resf[oc] = fmaxf(m, 0.f);
      }
      int py = half * 32 + rp, px = 2 * t + pc;
      ((float4*)pool1)[((size_t)n * 64 + py) * 64 + px] = res;
    }
  }
}

// ---------------- conv2 (4->8ch, 3x3 SAME) + relu + maxpool2 -> split bf16 ----------------
// R3 structure restored WITHOUT the VGPR-capping launch bound: all 4 row-pairs
// in flight (64 live accs), weights loaded once per (kr,ks) tap. LDS 36 KB ->
// 4 blocks/CU; expected ~110 VGPR, no spill.
__global__ __launch_bounds__(256) void k_conv2(
    const float* __restrict__ pool1, const float* __restrict__ w2,
    const float* __restrict__ b2, unsigned short* __restrict__ pool2h,
    unsigned short* __restrict__ pool2l) {
  __shared__ float p1[34 * 66 * 4];  // [row][col 0..65][4ch]; col0/col65 zero
  int half = blockIdx.x, n = blockIdx.y;
  int tid = threadIdx.x;
  int cy0 = half * 32;
  const float4* src = (const float4*)(pool1 + (size_t)n * 16384);
  for (int i = tid; i < 34 * 64; i += 256) {
    int r = i >> 6, c = i & 63;
    int iy = cy0 - 1 + r;
    float4 v = make_float4(0.f, 0.f, 0.f, 0.f);
    if (iy >= 0 && iy < 64) v = src[iy * 64 + c];
    ((float4*)p1)[r * 66 + c + 1] = v;
  }
  if (tid < 68) {
    int r = tid >> 1, c = (tid & 1) ? 65 : 0;
    ((float4*)p1)[r * 66 + c] = make_float4(0.f, 0.f, 0.f, 0.f);
  }
  float bb[8];
#pragma unroll
  for (int o = 0; o < 8; ++o) bb[o] = b2[o];
  __syncthreads();
  int x = tid & 63;  // conv column
  int w = tid >> 6;  // wave -> pool rows w, w+4, w+8, w+12
  const float4* p14 = (const float4*)p1;
  float acc[4][2][8];
#pragma unroll
  for (int rpi = 0; rpi < 4; ++rpi)
#pragma unroll
    for (int rr = 0; rr < 2; ++rr)
#pragma unroll
      for (int oc = 0; oc < 8; ++oc) acc[rpi][rr][oc] = bb[oc];
#pragma unroll
  for (int kr = 0; kr < 3; ++kr) {
#pragma unroll
    for (int ks = 0; ks < 3; ++ks) {
      float wv[8][4];  // uniform loads -> scalar regs, amortized over 256 FMA
#pragma unroll
      for (int oc = 0; oc < 8; ++oc)
#pragma unroll
        for (int ic = 0; ic < 4; ++ic)
          wv[oc][ic] = w2[((oc * 4 + ic) * 3 + kr) * 3 + ks];
#pragma unroll
      for (int rpi = 0; rpi < 4; ++rpi) {
        int rp = w + 4 * rpi;
        float4 v0 = p14[(2 * rp + kr) * 66 + x + ks];
        float4 v1 = p14[(2 * rp + 1 + kr) * 66 + x + ks];
#pragma unroll
        for (int oc = 0; oc < 8; ++oc) {
          acc[rpi][0][oc] += v0.x * wv[oc][0] + v0.y * wv[oc][1] +
                             v0.z * wv[oc][2] + v0.w * wv[oc][3];
          acc[rpi][1][oc] += v1.x * wv[oc][0] + v1.y * wv[oc][1] +
                             v1.z * wv[oc][2] + v1.w * wv[oc][3];
        }
      }
    }
  }
#pragma unroll
  for (int rpi = 0; rpi < 4; ++rpi) {
    int rp = w + 4 * rpi;
    int py = half * 16 + rp, px = x >> 1;
#pragma unroll
    for (int oc = 0; oc < 8; ++oc) {
      float m = fmaxf(fmaxf(acc[rpi][0][oc], acc[rpi][1][oc]), 0.f);
      m = fmaxf(m, __shfl_xor(m, 1));
      if ((x & 1) == 0) {
        size_t idx = (size_t)n * 8192 + oc * 1024 + py * 32 + px;
        unsigned short mh = f2bf(m);
        pool2h[idx] = mh;
        pool2l[idx] = f2bf(m - bf2f(mh));
      }
    }
  }
}

// ---------------- cast out_w -> split bf16; zero xfc & loss ----------------
__global__ __launch_bounds__(256) void k_cast(
    const float* __restrict__ out_w, unsigned short* __restrict__ whi,
    unsigned short* __restrict__ wlo, float* __restrict__ xfc,
    float* __restrict__ loss) {
  int gid = blockIdx.x * 256 + threadIdx.x;  // 131072 = 524288/4
  if (gid == 0) *loss = 0.f;
  float4 v = ((const float4*)out_w)[gid];
  ushort4 h, l;
  h.x = f2bf(v.x); l.x = f2bf(v.x - bf2f(h.x));
  h.y = f2bf(v.y); l.y = f2bf(v.y - bf2f(h.y));
  h.z = f2bf(v.z); l.z = f2bf(v.z - bf2f(h.z));
  h.w = f2bf(v.w); l.w = f2bf(v.w - bf2f(h.w));
  ((ushort4*)whi)[gid] = h;
  ((ushort4*)wlo)[gid] = l;
  if (gid < N_ITEM * 64) xfc[gid] = 0.f;
}

// ---------------- FC: split-bf16 MFMA GEMM, M=840 N=64, K chunks of 256 ----------------
__global__ __launch_bounds__(64) void k_fc(
    const unsigned short* __restrict__ pool2h, const unsigned short* __restrict__ pool2l,
    const unsigned short* __restrict__ whi, const unsigned short* __restrict__ wlo,
    float* __restrict__ xfc) {
  int mt = blockIdx.x, kc = blockIdx.y;
  int lane = threadIdx.x;
  int ml = lane & 15, q = lane >> 4;
  int row = mt * 16 + ml; if (row > N_ITEM - 1) row = N_ITEM - 1;  // clamp (stores guarded)
  size_t k0 = (size_t)kc * 256 + q * 8;
  const bh8* Ah = (const bh8*)(pool2h + (size_t)row * 8192 + k0);
  const bh8* Al = (const bh8*)(pool2l + (size_t)row * 8192 + k0);
  const bh8* Bh[4], * Bl[4];
#pragma unroll
  for (int nb = 0; nb < 4; ++nb) {
    Bh[nb] = (const bh8*)(whi + (size_t)(nb * 16 + ml) * 8192 + k0);
    Bl[nb] = (const bh8*)(wlo + (size_t)(nb * 16 + ml) * 8192 + k0);
  }
  f32x4 acc[4];
#pragma unroll
  for (int nb = 0; nb < 4; ++nb) acc[nb] = (f32x4){0.f, 0.f, 0.f, 0.f};
#pragma unroll
  for (int st = 0; st < 8; ++st) {
    bh8 ah = Ah[st * 4], al = Al[st * 4];
#pragma unroll
    for (int nb = 0; nb < 4; ++nb) {
      bh8 bhv = Bh[nb][st * 4], blv = Bl[nb][st * 4];
      acc[nb] = __builtin_amdgcn_mfma_f32_16x16x32_bf16(ah, bhv, acc[nb], 0, 0, 0);
      acc[nb] = __builtin_amdgcn_mfma_f32_16x16x32_bf16(ah, blv, acc[nb], 0, 0, 0);
      acc[nb] = __builtin_amdgcn_mfma_f32_16x16x32_bf16(al, bhv, acc[nb], 0, 0, 0);
    }
  }
#pragma unroll
  for (int r = 0; r < 4; ++r) {
    int mr = mt * 16 + q * 4 + r;
    if (mr < N_ITEM) {
      float* dst = xfc + (size_t)mr * 64 + ml;
#pragma unroll
      for (int nb = 0; nb < 4; ++nb) atomicAdd(dst + nb * 16, acc[nb][r]);
    }
  }
}

// ---------------- per-group, per-column batch norm (ddof=1) ----------------
__global__ __launch_bounds__(256) void k_norm(
    const float* __restrict__ xfc, float* __restrict__ item) {
  __shared__ float red[256];
  int grp = blockIdx.x >> 6;
  int o = blockIdx.x & 63;
  int base = grp ? N_CELL : 0;
  int N = grp ? N_DRUG : N_CELL;
  int tid = threadIdx.x;
  float s = 0.f;
  for (int i = tid; i < N; i += 256) s += xfc[(size_t)(base + i) * 64 + o];
  red[tid] = s; __syncthreads();
  for (int w = 128; w > 0; w >>= 1) { if (tid < w) red[tid] += red[tid + w]; __syncthreads(); }
  float mean = red[0] / (float)N;
  __syncthreads();
  float sq = 0.f;
  for (int i = tid; i < N; i += 256) {
    float d = xfc[(size_t)(base + i) * 64 + o] - mean;
    sq += d * d;
  }
  red[tid] = sq; __syncthreads();
  for (int w = 128; w > 0; w >>= 1) { if (tid < w) red[tid] += red[tid + w]; __syncthreads(); }
  float inv_std = 1.f / sqrtf(red[0] / (float)(N - 1));
  for (int i = tid; i < N; i += 256)
    item[(size_t)(base + i) * 64 + o] = (xfc[(size_t)(base + i) * 64 + o] - mean) * inv_std;
}

// ---------------- interact (2-hop attention) + agg GEMV ----------------
__global__ __launch_bounds__(256) void k_interact(
    const int* __restrict__ cell_nbr, const int* __restrict__ drug_nbr,
    const float* __restrict__ protein, const float* __restrict__ item,
    const float* __restrict__ agg_w, const float* __restrict__ agg_b,
    float* __restrict__ emb) {
  __shared__ float pb[128 * 65];
  __shared__ float item_s[64];
  __shared__ float sc[128];
  __shared__ float hop_out[128];
  __shared__ float red[256];
  int n = blockIdx.x;
  int tid = threadIdx.x;
  const int* nbr = (n < N_CELL) ? (cell_nbr + (size_t)n * 256)
                                : (drug_nbr + (size_t)(n - N_CELL) * 256);
  if (tid < 64) item_s[tid] = item[(size_t)n * 64 + tid];
  __syncthreads();
  for (int h = 0; h < 2; ++h) {
    for (int e = tid; e < 8192; e += 256) {
      int k = e >> 6, d = e & 63;
      int idx = nbr[h * 128 + k];
      pb[k * 65 + d] = protein[(size_t)idx * 64 + d];
    }
    __syncthreads();
    {
      int k = tid >> 1, halfd = tid & 1;
      int d0 = halfd * 32;
      float p = 0.f;
#pragma unroll
      for (int d = 0; d < 32; ++d) p += item_s[d0 + d] * pb[k * 65 + d0 + d];
      p += __shfl_xor(p, 1);
      if (halfd == 0) sc[k] = p;
    }
    __syncthreads();
    if (tid < 64) {
      float a = sc[tid], b = sc[tid + 64];
      float m = fmaxf(a, b);
#pragma unroll
      for (int off = 32; off > 0; off >>= 1) m = fmaxf(m, __shfl_xor(m, off));
      float e0 = __expf(a - m), e1 = __expf(b - m);
      float s = e0 + e1;
#pragma unroll
      for (int off = 32; off > 0; off >>= 1) s += __shfl_xor(s, off);
      float inv = 1.f / s;
      sc[tid] = e0 * inv; sc[tid + 64] = e1 * inv;
    }
    __syncthreads();
    {
      int d = tid & 63, kq = tid >> 6;
      float p = 0.f;
#pragma unroll
      for (int k = 0; k < 32; ++k) {
        int kk = kq * 32 + k;
        p += sc[kk] * pb[kk * 65 + d];
      }
      red[tid] = p;
    }
    __syncthreads();
    if (tid < 64)
      hop_out[h * 64 + tid] = red[tid] + red[tid + 64] + red[tid + 128] + red[tid + 192];
    __syncthreads();
  }
  {
    int o = tid & 63, jq = tid >> 6;
    float p = 0.f;
#pragma unroll
    for (int j = 0; j < 32; ++j) {
      int jj = jq * 32 + j;
      p += hop_out[jj] * agg_w[(size_t)o * 128 + jj];
    }
    red[tid] = p;
  }
  __syncthreads();
  if (tid < 64)
    emb[(size_t)n * 64 + tid] =
        red[tid] + red[tid + 64] + red[tid + 128] + red[tid + 192] + agg_b[tid];
}

// ---------------- precompute V[c] = comb_w^T @ cell_emb[c]  (76 x 128) ----------------
__global__ __launch_bounds__(128) void k_cellv(
    const float* __restrict__ emb, const float* __restrict__ comb_w,
    float* __restrict__ V) {
  __shared__ float ce[64];
  int c = blockIdx.x;
  int j = threadIdx.x;
  if (j < 64) ce[j] = emb[(size_t)c * 64 + j];
  __syncthreads();
  float s = 0.f;
#pragma unroll
  for (int o = 0; o < 64; ++o) s += comb_w[(size_t)o * 128 + j] * ce[o];
  V[(size_t)c * 128 + j] = s;
}

// ---------------- final scoring: therapy = cat(e1,e2) . V[c], toxic = e1.e2 ----------------
__global__ __launch_bounds__(256) void k_score(
    const int* __restrict__ data, const float* __restrict__ emb,
    const float* __restrict__ V, float* __restrict__ out,
    float* __restrict__ loss) {
  __shared__ float racc[4];
  int tid = threadIdx.x;
  int lane = tid & 63;
  int w = tid >> 6;
  int b = blockIdx.x * 4 + w;
  int c = data[b * 3 + 0], d1 = data[b * 3 + 1], d2 = data[b * 3 + 2];
  float ce = emb[(size_t)c * 64 + lane];
  float e1 = emb[(size_t)(N_CELL + d1) * 64 + lane];
  float e2 = emb[(size_t)(N_CELL + d2) * 64 + lane];
  float v1 = V[(size_t)c * 128 + lane];
  float v2 = V[(size_t)c * 128 + 64 + lane];
  float th = e1 * v1 + e2 * v2;
  float tx = e1 * e2;
  float rg = ce * ce + e1 * e1 + e2 * e2;
#pragma unroll
  for (int off = 32; off > 0; off >>= 1) {
    th += __shfl_xor(th, off);
    tx += __shfl_xor(tx, off);
    rg += __shfl_xor(rg, off);
  }
  if (lane == 0) { out[b] = th - tx; racc[w] = rg; }
  __syncthreads();
  if (tid == 0) atomicAdd(loss, 0.5f * (racc[0] + racc[1] + racc[2] + racc[3]));
}

// ---------------- node regularization (6 gathered rows) ----------------
__global__ __launch_bounds__(256) void k_nodereg(
    const int* __restrict__ data, const int* __restrict__ cell_nbr,
    const int* __restrict__ drug_nbr, const float* __restrict__ protein,
    float* __restrict__ loss) {
  __shared__ float red[256];
  int j = blockIdx.x;  // 0..5
  int hop = j / 3, which = j % 3;
  int row = data[hop * 3 + which];
  const int* nbr = (which == 0) ? (cell_nbr + (size_t)row * 256)
                                : (drug_nbr + (size_t)row * 256);
  int tid = threadIdx.x;
  float acc = 0.f;
  for (int e = tid; e < 16384; e += 256) {
    int k = e >> 6, d = e & 63;
    float v = protein[(size_t)nbr[k] * 64 + d];
    acc += v * v;
  }
  red[tid] = acc; __syncthreads();
  for (int w = 128; w > 0; w >>= 1) { if (tid < w) red[tid] += red[tid + w]; __syncthreads(); }
  if (tid == 0) atomicAdd(loss, 0.5f * red[0]);
}

__global__ void k_finalize(const float* __restrict__ loss, float* __restrict__ out) {
  if (threadIdx.x == 0) out[BATCH] = loss[0] * (1e-6f / 4096.f);
}

extern "C" void kernel_launch(void* const* d_in, const int* in_sizes, int n_in,
                              void* d_out, int out_size, void* d_ws, size_t ws_size,
                              hipStream_t stream) {
  const int*   data      = (const int*)d_in[0];
  const int*   cell_nbr  = (const int*)d_in[1];
  const int*   drug_nbr  = (const int*)d_in[2];
  const float* protein   = (const float*)d_in[3];
  const float* cell_pre  = (const float*)d_in[4];
  const float* drug_pre  = (const float*)d_in[5];
  const float* w1        = (const float*)d_in[6];
  const float* b1        = (const float*)d_in[7];
  const float* w2        = (const float*)d_in[8];
  const float* b2        = (const float*)d_in[9];
  const float* out_w     = (const float*)d_in[10];
  const float* agg_w     = (const float*)d_in[12];
  const float* agg_b     = (const float*)d_in[13];
  const float* comb_w    = (const float*)d_in[14];
  float* out = (float*)d_out;
  char* base = (char*)d_ws;
  float* pool1            = (float*)base;
  unsigned short* pool2h  = (unsigned short*)(base + POOL2H_B);
  unsigned short* pool2l  = (unsigned short*)(base + POOL2L_B);
  unsigned short* whi     = (unsigned short*)(base + WHI_B);
  unsigned short* wlo     = (unsigned short*)(base + WLO_B);
  float* xfc              = (float*)(base + XFC_B);
  float* item             = (float*)(base + ITEM_B);
  float* emb              = (float*)(base + EMB_B);
  float* V                = (float*)(base + V_B);
  float* loss             = (float*)(base + LOSS_B);

  k_conv1<<<dim3(2, 840), 256, 0, stream>>>(cell_pre, drug_pre, w1, b1, pool1);
  k_conv2<<<dim3(2, 840), 256, 0, stream>>>(pool1, w2, b2, pool2h, pool2l);
  k_cast<<<512, 256, 0, stream>>>(out_w, whi, wlo, xfc, loss);
  k_fc<<<dim3(53, 32), 64, 0, stream>>>(pool2h, pool2l, whi, wlo, xfc);
  k_norm<<<128, 256, 0, stream>>>(xfc, item);
  k_interact<<<840, 256, 0, stream>>>(cell_nbr, drug_nbr, protein, item, agg_w, agg_b, emb);
  k_cellv<<<N_CELL, 128, 0, stream>>>(emb, comb_w, V);
  k_score<<<1024, 256, 0, stream>>>(data, emb, V, out, loss);
  k_nodereg<<<6, 256, 0, stream>>>(data, cell_nbr, drug_nbr, protein, loss);
  k_finalize<<<1, 64, 0, stream>>>(loss, out);
}

// Round 6
// 256.339 us; speedup vs baseline: 1.4920x; 1.1777x over previous
//
#include <hip/hip_runtime.h>
#include <hip/hip_bf16.h>
#include <math.h>

#define N_CELL 76
#define N_DRUG 764
#define N_ITEM 840
#define BATCH  4096

// ws layout (byte offsets)
// Phase A (convs): pool1 f32 [840][64][64][4] : 0 .. 55,050,240
//                  pool2h bf16 [840][8192]    : 55,050,240 .. 68,812,800
//                  pool2l bf16 [840][8192]    : 68,812,800 .. 82,575,360
// Phase B (after conv2, aliases dead pool1):
//                  whi bf16 [64][8192], wlo, xfc, item, emb, V, loss
#define POOL2H_B 55050240u
#define POOL2L_B 68812800u
#define WHI_B    0u
#define WLO_B    1048576u
#define XFC_B    2097152u
#define ITEM_B   2312192u
#define EMB_B    2527232u
#define V_B      2742272u
#define LOSS_B   2781184u

typedef short bh8 __attribute__((ext_vector_type(8)));
typedef short bh4 __attribute__((ext_vector_type(4)));
typedef float f32x4 __attribute__((ext_vector_type(4)));

static __device__ inline unsigned short f2bf(float f) {
  union { float f; unsigned u; } v; v.f = f;
  unsigned r = v.u + 0x7FFFu + ((v.u >> 16) & 1u);  // RNE (no NaN inputs here)
  return (unsigned short)(r >> 16);
}
static __device__ inline float bf2f(unsigned short h) {
  union { unsigned u; float f; } v; v.u = ((unsigned)h) << 16;
  return v.f;
}
// lo residual via truncation (residual <= 2^-9|a|, trunc err <= 2^-17|a|)
static __device__ inline unsigned short f2bf_lo(float f, unsigned short h) {
  union { float f; unsigned u; } a; a.f = f - bf2f(h);
  return (unsigned short)(a.u >> 16);
}

// ---------------- conv1 (1->4ch, 3x3 SAME) + relu + maxpool2 ----------------
// (unchanged — isolating the conv2 delta; its true cost shows next profile)
__global__ __launch_bounds__(256) void k_conv1(
    const float* __restrict__ cell_pre, const float* __restrict__ drug_pre,
    const float* __restrict__ w1, const float* __restrict__ b1,
    float* __restrict__ pool1) {
  __shared__ float img[66 * 128];
  int half = blockIdx.x, n = blockIdx.y;
  int tid = threadIdx.x;
  int cy0 = half * 64;
  const float* src = (n < N_CELL) ? (cell_pre + (size_t)n * 16384)
                                  : (drug_pre + (size_t)(n - N_CELL) * 16384);
  for (int i = tid; i < 66 * 32; i += 256) {
    int r = i >> 5, c = i & 31;
    int iy = cy0 - 1 + r;
    float4 v = make_float4(0.f, 0.f, 0.f, 0.f);
    if (iy >= 0 && iy < 128) v = ((const float4*)src)[iy * 32 + c];
    ((float4*)img)[i] = v;
  }
  float wv[4][9], bb[4];
#pragma unroll
  for (int c = 0; c < 4; ++c) {
    bb[c] = b1[c];
#pragma unroll
    for (int j = 0; j < 9; ++j) wv[c][j] = w1[c * 9 + j];
  }
  __syncthreads();
  int t = tid & 31;
  int g = tid >> 5;
  const float4* img4 = (const float4*)img;
#pragma unroll 1
  for (int rpi = 0; rpi < 4; ++rpi) {
    int rp = g + 8 * rpi;
    int ly = 2 * rp;
    float4 rowv[4]; float lo[4], hi[4];
#pragma unroll
    for (int rr = 0; rr < 4; ++rr) {
      rowv[rr] = img4[(ly + rr) * 32 + t];
      float l = __shfl_up(rowv[rr].w, 1);
      float h = __shfl_down(rowv[rr].x, 1);
      lo[rr] = (t == 0) ? 0.f : l;
      hi[rr] = (t == 31) ? 0.f : h;
    }
    float a[2][4][4];
#pragma unroll
    for (int orow = 0; orow < 2; ++orow)
#pragma unroll
      for (int oc = 0; oc < 4; ++oc)
#pragma unroll
        for (int c = 0; c < 4; ++c) a[orow][oc][c] = bb[oc];
#pragma unroll
    for (int orow = 0; orow < 2; ++orow) {
#pragma unroll
      for (int kr = 0; kr < 3; ++kr) {
        int rr = orow + kr;
        float in[6] = {lo[rr], rowv[rr].x, rowv[rr].y, rowv[rr].z, rowv[rr].w, hi[rr]};
#pragma unroll
        for (int ks = 0; ks < 3; ++ks)
#pragma unroll
          for (int oc = 0; oc < 4; ++oc) {
            float w = wv[oc][kr * 3 + ks];
#pragma unroll
            for (int c = 0; c < 4; ++c) a[orow][oc][c] += in[c + ks] * w;
          }
      }
    }
#pragma unroll
    for (int pc = 0; pc < 2; ++pc) {
      float4 res;
      float* resf = (float*)&res;
#pragma unroll
      for (int oc = 0; oc < 4; ++oc) {
        float m = fmaxf(fmaxf(a[0][oc][2 * pc], a[0][oc][2 * pc + 1]),
                        fmaxf(a[1][oc][2 * pc], a[1][oc][2 * pc + 1]));
        resf[oc] = fmaxf(m, 0.f);
      }
      int py = half * 32 + rp, px = 2 * t + pc;
      ((float4*)pool1)[((size_t)n * 64 + py) * 64 + px] = res;
    }
  }
}

// ---------------- conv2 via MFMA (split bf16) ----------------
// Implicit GEMM: M=16 px strip, N=16 = 8 oc x 2 row-variants, K=64:
// k<48 = (input row r 0..3, tap ks 0..2, ic 0..3); k=48 = bias (A=1.0);
// k 49..63 zero. B[col=(oc,yv)][k] = w2[oc][ic][r-yv][ks] when 0<=r-yv<=2.
// LDS holds split-bf16 h/l planes (converted once at staging). 6 MFMA/set.
__global__ __launch_bounds__(256) void k_conv2(
    const float* __restrict__ pool1, const float* __restrict__ w2,
    const float* __restrict__ b2, unsigned short* __restrict__ pool2h,
    unsigned short* __restrict__ pool2l) {
  __shared__ unsigned short lh[34 * 66 * 4];  // [row][col 0..65][4ic] hi
  __shared__ unsigned short ll[34 * 66 * 4];  // lo plane
  int half = blockIdx.x, n = blockIdx.y;
  int tid = threadIdx.x;
  int cy0 = half * 32;
  const float4* src = (const float4*)(pool1 + (size_t)n * 16384);
  for (int i = tid; i < 34 * 64; i += 256) {
    int r = i >> 6, c = i & 63;
    int iy = cy0 - 1 + r;
    float4 v = make_float4(0.f, 0.f, 0.f, 0.f);
    if (iy >= 0 && iy < 64) v = src[iy * 64 + c];
    ushort4 h, l;
    h.x = f2bf(v.x); l.x = f2bf_lo(v.x, h.x);
    h.y = f2bf(v.y); l.y = f2bf_lo(v.y, h.y);
    h.z = f2bf(v.z); l.z = f2bf_lo(v.z, h.z);
    h.w = f2bf(v.w); l.w = f2bf_lo(v.w, h.w);
    ((ushort4*)lh)[r * 66 + c + 1] = h;
    ((ushort4*)ll)[r * 66 + c + 1] = l;
  }
  if (tid < 68) {
    int r = tid >> 1, c = (tid & 1) ? 65 : 0;
    ushort4 z = make_ushort4(0, 0, 0, 0);
    ((ushort4*)lh)[r * 66 + c] = z;
    ((ushort4*)ll)[r * 66 + c] = z;
  }
  int wv_ = tid >> 6;
  int lane = tid & 63;
  int ml = lane & 15, q = lane >> 4;
  int oc_b = ml & 7, yv = ml >> 3;
  // ---- build B fragments (once per wave; lane = col ml, k = q*8+j) ----
  bh8 Bh[2], Bl[2];
#pragma unroll
  for (int ch = 0; ch < 2; ++ch) {
#pragma unroll
    for (int j = 0; j < 8; ++j) {
      int kg = ch * 32 + q * 8 + j;
      float v = 0.f;
      if (kg < 48) {
        int r = kg / 12, rem = kg - r * 12;
        int ks = rem >> 2, ic = rem & 3;
        int kr = r - yv;
        if (kr >= 0 && kr <= 2) v = w2[(oc_b * 4 + ic) * 9 + kr * 3 + ks];
      } else if (kg == 48) {
        v = b2[oc_b];
      }
      unsigned short h = f2bf(v);
      Bh[ch][j] = (short)h;
      Bl[ch][j] = (short)f2bf_lo(v, h);
    }
  }
  // ---- per-lane A cell offsets (cell c: r=c/3, ks=c%3; bh4 idx = (2rp+r)*66 + x0+ml+ks) ----
  int c0 = 2 * q, c1 = 2 * q + 1;            // chunk0 cells (q=0..3 -> c 0..7)
  int c2 = 8 + 2 * q, c3 = 9 + 2 * q;        // chunk1 cells (valid q<2)
  if (c2 > 11) { c2 = 8; c3 = 9; }           // clamp for masked lanes
  int r0 = (c0 * 86) >> 8, s0 = c0 - 3 * r0;
  int r1 = (c1 * 86) >> 8, s1 = c1 - 3 * r1;
  int r2 = (c2 * 86) >> 8, s2 = c2 - 3 * r2;
  int r3 = (c3 * 86) >> 8, s3 = c3 - 3 * r3;
  int x0 = (wv_ & 3) << 4;  // each wave owns one 16-px x-strip
  int off0 = r0 * 66 + x0 + ml + s0;
  int off1 = r1 * 66 + x0 + ml + s1;
  int off2 = r2 * 66 + x0 + ml + s2;
  int off3 = r3 * 66 + x0 + ml + s3;
  __syncthreads();
  const bh4* lh4 = (const bh4*)lh;
  const bh4* ll4 = (const bh4*)ll;
  union BH8U { bh8 v; struct { bh4 lo, hi; } s; };
#pragma unroll 1
  for (int rp = 0; rp < 16; ++rp) {
    int base = 2 * rp * 66;
    BH8U ah0, al0, ah1, al1;
    ah0.s.lo = lh4[base + off0]; ah0.s.hi = lh4[base + off1];
    al0.s.lo = ll4[base + off0]; al0.s.hi = ll4[base + off1];
    if (q < 2) {
      ah1.s.lo = lh4[base + off2]; ah1.s.hi = lh4[base + off3];
      al1.s.lo = ll4[base + off2]; al1.s.hi = ll4[base + off3];
    } else {
#pragma unroll
      for (int j = 0; j < 8; ++j) { ah1.v[j] = 0; al1.v[j] = 0; }
      if (q == 2) ah1.v[0] = (short)0x3F80;  // bf16 1.0 -> bias row k=48
    }
    f32x4 accA = {0.f, 0.f, 0.f, 0.f}, accB = accA;
    accA = __builtin_amdgcn_mfma_f32_16x16x32_bf16(ah0.v, Bh[0], accA, 0, 0, 0);
    accA = __builtin_amdgcn_mfma_f32_16x16x32_bf16(ah0.v, Bl[0], accA, 0, 0, 0);
    accA = __builtin_amdgcn_mfma_f32_16x16x32_bf16(al0.v, Bh[0], accA, 0, 0, 0);
    accB = __builtin_amdgcn_mfma_f32_16x16x32_bf16(ah1.v, Bh[1], accB, 0, 0, 0);
    accB = __builtin_amdgcn_mfma_f32_16x16x32_bf16(ah1.v, Bl[1], accB, 0, 0, 0);
    accB = __builtin_amdgcn_mfma_f32_16x16x32_bf16(al1.v, Bh[1], accB, 0, 0, 0);
    // D: col=ml=(oc,yv), row=q*4+reg = px offset in strip
    float d0 = accA[0] + accB[0], d1 = accA[1] + accB[1];
    float d2 = accA[2] + accB[2], d3 = accA[3] + accB[3];
    float m0 = fmaxf(d0, d1), m1 = fmaxf(d2, d3);      // x-pool
    float o0 = __shfl_xor(m0, 8), o1 = __shfl_xor(m1, 8);  // y-pool partner
    m0 = fmaxf(fmaxf(m0, o0), 0.f);
    m1 = fmaxf(fmaxf(m1, o1), 0.f);
    if (yv == 0) {
      unsigned short h0 = f2bf(m0), h1 = f2bf(m1);
      unsigned short l0 = f2bf(m0 - bf2f(h0)), l1 = f2bf(m1 - bf2f(h1));
      int PR = half * 16 + rp;
      unsigned ui = (unsigned)n * 4096u + (unsigned)oc_b * 512u +
                    (unsigned)PR * 16u + (unsigned)(x0 >> 2) + (unsigned)q;
      ((unsigned*)pool2h)[ui] = (unsigned)h0 | ((unsigned)h1 << 16);
      ((unsigned*)pool2l)[ui] = (unsigned)l0 | ((unsigned)l1 << 16);
    }
  }
}

// ---------------- cast out_w -> split bf16; zero xfc & loss ----------------
__global__ __launch_bounds__(256) void k_cast(
    const float* __restrict__ out_w, unsigned short* __restrict__ whi,
    unsigned short* __restrict__ wlo, float* __restrict__ xfc,
    float* __restrict__ loss) {
  int gid = blockIdx.x * 256 + threadIdx.x;  // 131072 = 524288/4
  if (gid == 0) *loss = 0.f;
  float4 v = ((const float4*)out_w)[gid];
  ushort4 h, l;
  h.x = f2bf(v.x); l.x = f2bf(v.x - bf2f(h.x));
  h.y = f2bf(v.y); l.y = f2bf(v.y - bf2f(h.y));
  h.z = f2bf(v.z); l.z = f2bf(v.z - bf2f(h.z));
  h.w = f2bf(v.w); l.w = f2bf(v.w - bf2f(h.w));
  ((ushort4*)whi)[gid] = h;
  ((ushort4*)wlo)[gid] = l;
  if (gid < N_ITEM * 64) xfc[gid] = 0.f;
}

// ---------------- FC: split-bf16 MFMA GEMM, M=840 N=64, K chunks of 256 ----------------
__global__ __launch_bounds__(64) void k_fc(
    const unsigned short* __restrict__ pool2h, const unsigned short* __restrict__ pool2l,
    const unsigned short* __restrict__ whi, const unsigned short* __restrict__ wlo,
    float* __restrict__ xfc) {
  int mt = blockIdx.x, kc = blockIdx.y;
  int lane = threadIdx.x;
  int ml = lane & 15, q = lane >> 4;
  int row = mt * 16 + ml; if (row > N_ITEM - 1) row = N_ITEM - 1;  // clamp (stores guarded)
  size_t k0 = (size_t)kc * 256 + q * 8;
  const bh8* Ah = (const bh8*)(pool2h + (size_t)row * 8192 + k0);
  const bh8* Al = (const bh8*)(pool2l + (size_t)row * 8192 + k0);
  const bh8* Bh[4], * Bl[4];
#pragma unroll
  for (int nb = 0; nb < 4; ++nb) {
    Bh[nb] = (const bh8*)(whi + (size_t)(nb * 16 + ml) * 8192 + k0);
    Bl[nb] = (const bh8*)(wlo + (size_t)(nb * 16 + ml) * 8192 + k0);
  }
  f32x4 acc[4];
#pragma unroll
  for (int nb = 0; nb < 4; ++nb) acc[nb] = (f32x4){0.f, 0.f, 0.f, 0.f};
#pragma unroll
  for (int st = 0; st < 8; ++st) {
    bh8 ah = Ah[st * 4], al = Al[st * 4];
#pragma unroll
    for (int nb = 0; nb < 4; ++nb) {
      bh8 bhv = Bh[nb][st * 4], blv = Bl[nb][st * 4];
      acc[nb] = __builtin_amdgcn_mfma_f32_16x16x32_bf16(ah, bhv, acc[nb], 0, 0, 0);
      acc[nb] = __builtin_amdgcn_mfma_f32_16x16x32_bf16(ah, blv, acc[nb], 0, 0, 0);
      acc[nb] = __builtin_amdgcn_mfma_f32_16x16x32_bf16(al, bhv, acc[nb], 0, 0, 0);
    }
  }
#pragma unroll
  for (int r = 0; r < 4; ++r) {
    int mr = mt * 16 + q * 4 + r;
    if (mr < N_ITEM) {
      float* dst = xfc + (size_t)mr * 64 + ml;
#pragma unroll
      for (int nb = 0; nb < 4; ++nb) atomicAdd(dst + nb * 16, acc[nb][r]);
    }
  }
}

// ---------------- per-group, per-column batch norm (ddof=1) ----------------
__global__ __launch_bounds__(256) void k_norm(
    const float* __restrict__ xfc, float* __restrict__ item) {
  __shared__ float red[256];
  int grp = blockIdx.x >> 6;
  int o = blockIdx.x & 63;
  int base = grp ? N_CELL : 0;
  int N = grp ? N_DRUG : N_CELL;
  int tid = threadIdx.x;
  float s = 0.f;
  for (int i = tid; i < N; i += 256) s += xfc[(size_t)(base + i) * 64 + o];
  red[tid] = s; __syncthreads();
  for (int w = 128; w > 0; w >>= 1) { if (tid < w) red[tid] += red[tid + w]; __syncthreads(); }
  float mean = red[0] / (float)N;
  __syncthreads();
  float sq = 0.f;
  for (int i = tid; i < N; i += 256) {
    float d = xfc[(size_t)(base + i) * 64 + o] - mean;
    sq += d * d;
  }
  red[tid] = sq; __syncthreads();
  for (int w = 128; w > 0; w >>= 1) { if (tid < w) red[tid] += red[tid + w]; __syncthreads(); }
  float inv_std = 1.f / sqrtf(red[0] / (float)(N - 1));
  for (int i = tid; i < N; i += 256)
    item[(size_t)(base + i) * 64 + o] = (xfc[(size_t)(base + i) * 64 + o] - mean) * inv_std;
}

// ---------------- interact (2-hop attention) + agg GEMV ----------------
__global__ __launch_bounds__(256) void k_interact(
    const int* __restrict__ cell_nbr, const int* __restrict__ drug_nbr,
    const float* __restrict__ protein, const float* __restrict__ item,
    const float* __restrict__ agg_w, const float* __restrict__ agg_b,
    float* __restrict__ emb) {
  __shared__ float pb[128 * 65];
  __shared__ float item_s[64];
  __shared__ float sc[128];
  __shared__ float hop_out[128];
  __shared__ float red[256];
  int n = blockIdx.x;
  int tid = threadIdx.x;
  const int* nbr = (n < N_CELL) ? (cell_nbr + (size_t)n * 256)
                                : (drug_nbr + (size_t)(n - N_CELL) * 256);
  if (tid < 64) item_s[tid] = item[(size_t)n * 64 + tid];
  __syncthreads();
  for (int h = 0; h < 2; ++h) {
    for (int e = tid; e < 8192; e += 256) {
      int k = e >> 6, d = e & 63;
      int idx = nbr[h * 128 + k];
      pb[k * 65 + d] = protein[(size_t)idx * 64 + d];
    }
    __syncthreads();
    {
      int k = tid >> 1, halfd = tid & 1;
      int d0 = halfd * 32;
      float p = 0.f;
#pragma unroll
      for (int d = 0; d < 32; ++d) p += item_s[d0 + d] * pb[k * 65 + d0 + d];
      p += __shfl_xor(p, 1);
      if (halfd == 0) sc[k] = p;
    }
    __syncthreads();
    if (tid < 64) {
      float a = sc[tid], b = sc[tid + 64];
      float m = fmaxf(a, b);
#pragma unroll
      for (int off = 32; off > 0; off >>= 1) m = fmaxf(m, __shfl_xor(m, off));
      float e0 = __expf(a - m), e1 = __expf(b - m);
      float s = e0 + e1;
#pragma unroll
      for (int off = 32; off > 0; off >>= 1) s += __shfl_xor(s, off);
      float inv = 1.f / s;
      sc[tid] = e0 * inv; sc[tid + 64] = e1 * inv;
    }
    __syncthreads();
    {
      int d = tid & 63, kq = tid >> 6;
      float p = 0.f;
#pragma unroll
      for (int k = 0; k < 32; ++k) {
        int kk = kq * 32 + k;
        p += sc[kk] * pb[kk * 65 + d];
      }
      red[tid] = p;
    }
    __syncthreads();
    if (tid < 64)
      hop_out[h * 64 + tid] = red[tid] + red[tid + 64] + red[tid + 128] + red[tid + 192];
    __syncthreads();
  }
  {
    int o = tid & 63, jq = tid >> 6;
    float p = 0.f;
#pragma unroll
    for (int j = 0; j < 32; ++j) {
      int jj = jq * 32 + j;
      p += hop_out[jj] * agg_w[(size_t)o * 128 + jj];
    }
    red[tid] = p;
  }
  __syncthreads();
  if (tid < 64)
    emb[(size_t)n * 64 + tid] =
        red[tid] + red[tid + 64] + red[tid + 128] + red[tid + 192] + agg_b[tid];
}

// ---------------- precompute V[c] = comb_w^T @ cell_emb[c]  (76 x 128) ----------------
__global__ __launch_bounds__(128) void k_cellv(
    const float* __restrict__ emb, const float* __restrict__ comb_w,
    float* __restrict__ V) {
  __shared__ float ce[64];
  int c = blockIdx.x;
  int j = threadIdx.x;
  if (j < 64) ce[j] = emb[(size_t)c * 64 + j];
  __syncthreads();
  float s = 0.f;
#pragma unroll
  for (int o = 0; o < 64; ++o) s += comb_w[(size_t)o * 128 + j] * ce[o];
  V[(size_t)c * 128 + j] = s;
}

// ---------------- final scoring: therapy = cat(e1,e2) . V[c], toxic = e1.e2 ----------------
__global__ __launch_bounds__(256) void k_score(
    const int* __restrict__ data, const float* __restrict__ emb,
    const float* __restrict__ V, float* __restrict__ out,
    float* __restrict__ loss) {
  __shared__ float racc[4];
  int tid = threadIdx.x;
  int lane = tid & 63;
  int w = tid >> 6;
  int b = blockIdx.x * 4 + w;
  int c = data[b * 3 + 0], d1 = data[b * 3 + 1], d2 = data[b * 3 + 2];
  float ce = emb[(size_t)c * 64 + lane];
  float e1 = emb[(size_t)(N_CELL + d1) * 64 + lane];
  float e2 = emb[(size_t)(N_CELL + d2) * 64 + lane];
  float v1 = V[(size_t)c * 128 + lane];
  float v2 = V[(size_t)c * 128 + 64 + lane];
  float th = e1 * v1 + e2 * v2;
  float tx = e1 * e2;
  float rg = ce * ce + e1 * e1 + e2 * e2;
#pragma unroll
  for (int off = 32; off > 0; off >>= 1) {
    th += __shfl_xor(th, off);
    tx += __shfl_xor(tx, off);
    rg += __shfl_xor(rg, off);
  }
  if (lane == 0) { out[b] = th - tx; racc[w] = rg; }
  __syncthreads();
  if (tid == 0) atomicAdd(loss, 0.5f * (racc[0] + racc[1] + racc[2] + racc[3]));
}

// ---------------- node regularization (6 gathered rows) ----------------
__global__ __launch_bounds__(256) void k_nodereg(
    const int* __restrict__ data, const int* __restrict__ cell_nbr,
    const int* __restrict__ drug_nbr, const float* __restrict__ protein,
    float* __restrict__ loss) {
  __shared__ float red[256];
  int j = blockIdx.x;  // 0..5
  int hop = j / 3, which = j % 3;
  int row = data[hop * 3 + which];
  const int* nbr = (which == 0) ? (cell_nbr + (size_t)row * 256)
                                : (drug_nbr + (size_t)row * 256);
  int tid = threadIdx.x;
  float acc = 0.f;
  for (int e = tid; e < 16384; e += 256) {
    int k = e >> 6, d = e & 63;
    float v = protein[(size_t)nbr[k] * 64 + d];
    acc += v * v;
  }
  red[tid] = acc; __syncthreads();
  for (int w = 128; w > 0; w >>= 1) { if (tid < w) red[tid] += red[tid + w]; __syncthreads(); }
  if (tid == 0) atomicAdd(loss, 0.5f * red[0]);
}

__global__ void k_finalize(const float* __restrict__ loss, float* __restrict__ out) {
  if (threadIdx.x == 0) out[BATCH] = loss[0] * (1e-6f / 4096.f);
}

extern "C" void kernel_launch(void* const* d_in, const int* in_sizes, int n_in,
                              void* d_out, int out_size, void* d_ws, size_t ws_size,
                              hipStream_t stream) {
  const int*   data      = (const int*)d_in[0];
  const int*   cell_nbr  = (const int*)d_in[1];
  const int*   drug_nbr  = (const int*)d_in[2];
  const float* protein   = (const float*)d_in[3];
  const float* cell_pre  = (const float*)d_in[4];
  const float* drug_pre  = (const float*)d_in[5];
  const float* w1        = (const float*)d_in[6];
  const float* b1        = (const float*)d_in[7];
  const float* w2        = (const float*)d_in[8];
  const float* b2        = (const float*)d_in[9];
  const float* out_w     = (const float*)d_in[10];
  const float* agg_w     = (const float*)d_in[12];
  const float* agg_b     = (const float*)d_in[13];
  const float* comb_w    = (const float*)d_in[14];
  float* out = (float*)d_out;
  char* base = (char*)d_ws;
  float* pool1            = (float*)base;
  unsigned short* pool2h  = (unsigned short*)(base + POOL2H_B);
  unsigned short* pool2l  = (unsigned short*)(base + POOL2L_B);
  unsigned short* whi     = (unsigned short*)(base + WHI_B);
  unsigned short* wlo     = (unsigned short*)(base + WLO_B);
  float* xfc              = (float*)(base + XFC_B);
  float* item             = (float*)(base + ITEM_B);
  float* emb              = (float*)(base + EMB_B);
  float* V                = (float*)(base + V_B);
  float* loss             = (float*)(base + LOSS_B);

  k_conv1<<<dim3(2, 840), 256, 0, stream>>>(cell_pre, drug_pre, w1, b1, pool1);
  k_conv2<<<dim3(2, 840), 256, 0, stream>>>(pool1, w2, b2, pool2h, pool2l);
  k_cast<<<512, 256, 0, stream>>>(out_w, whi, wlo, xfc, loss);
  k_fc<<<dim3(53, 32), 64, 0, stream>>>(pool2h, pool2l, whi, wlo, xfc);
  k_norm<<<128, 256, 0, stream>>>(xfc, item);
  k_interact<<<840, 256, 0, stream>>>(cell_nbr, drug_nbr, protein, item, agg_w, agg_b, emb);
  k_cellv<<<N_CELL, 128, 0, stream>>>(emb, comb_w, V);
  k_score<<<1024, 256, 0, stream>>>(data, emb, V, out, loss);
  k_nodereg<<<6, 256, 0, stream>>>(data, cell_nbr, drug_nbr, protein, loss);
  k_finalize<<<1, 64, 0, stream>>>(loss, out);
}